// Round 1
// baseline (10286.089 us; speedup 1.0000x reference)
//
#include <hip/hip_runtime.h>
#include <hip/hip_bf16.h>
#include <stdint.h>

#define T_STEPS 512
#define BATCH   64
#define DIN     512
#define HID     1024
#define KDIM    1536        // HID + DIN (concat order: h then x)
#define NBLK    128         // persistent blocks (1 per CU, <=256 CUs)
#define HPB     8           // hidden cols per block
#define GCPB    32          // gate cols per block = 4 gates * HPB
#define NCHUNK  48          // KDIM / 32
#define KGRPS   192         // KDIM / 8

typedef __bf16 bf16x8 __attribute__((ext_vector_type(8)));
typedef float  f32x4  __attribute__((ext_vector_type(4)));
typedef unsigned short ushort_t;

__device__ __forceinline__ ushort_t f2bf(float f) {
    union { float f; unsigned u; } v; v.f = f;
    unsigned u = v.u;
    u += 0x7FFFu + ((u >> 16) & 1u);   // RNE
    return (ushort_t)(u >> 16);
}

__device__ __forceinline__ float sigmoidf_(float x) {
    return 1.0f / (1.0f + __expf(-x));
}

// ---------------- prep kernel 1: x fp32 -> bf16 ----------------
__global__ void cvt_x(const float* __restrict__ x, ushort_t* __restrict__ xb, int n8) {
    int i = blockIdx.x * blockDim.x + threadIdx.x;
    if (i >= n8) return;
    float4 v0 = ((const float4*)x)[2 * i];
    float4 v1 = ((const float4*)x)[2 * i + 1];
    uint4 o;
    o.x = (unsigned)f2bf(v0.x) | ((unsigned)f2bf(v0.y) << 16);
    o.y = (unsigned)f2bf(v0.z) | ((unsigned)f2bf(v0.w) << 16);
    o.z = (unsigned)f2bf(v1.x) | ((unsigned)f2bf(v1.y) << 16);
    o.w = (unsigned)f2bf(v1.z) | ((unsigned)f2bf(v1.w) << 16);
    ((uint4*)xb)[i] = o;
}

// ---------------- prep kernel 2: transpose W into per-block chunk-major bf16 ----------------
// Output layout: wt[blk][kgrp][n][8] bf16, blk=hiddencol/8, n = gate*8 + hiddencol%8, k = kgrp*8+j
__global__ void xpose_w(const float* __restrict__ Wi, const float* __restrict__ Wf,
                        const float* __restrict__ Wo, const float* __restrict__ Wg,
                        ushort_t* __restrict__ wt) {
    __shared__ float tile[64][65];
    int kt = blockIdx.x, nt = blockIdx.y, g = blockIdx.z;
    const float* W = (g == 0) ? Wi : (g == 1) ? Wf : (g == 2) ? Wo : Wg;
    int k0 = kt * 64, n0 = nt * 64;
    int c = threadIdx.x & 63, r0 = threadIdx.x >> 6;
#pragma unroll
    for (int i = 0; i < 16; ++i) {
        int r = r0 + i * 4;
        tile[r][c] = W[(size_t)(k0 + r) * HID + n0 + c];
    }
    __syncthreads();
#pragma unroll
    for (int p = 0; p < 2; ++p) {
        int q = threadIdx.x + p * 256;          // 512 chunks of 8
        int n_inner = q & 7;
        int kgl = (q >> 3) & 7;
        int bl = q >> 6;                        // 0..7
        int n = n0 + bl * 8 + n_inner;          // hidden col
        int blk = n >> 3;
        int nn = g * 8 + (n & 7);
        int kgrp = (k0 >> 3) + kgl;
        __align__(16) ushort_t tmp[8];
#pragma unroll
        for (int j = 0; j < 8; ++j) tmp[j] = f2bf(tile[kgl * 8 + j][bl * 8 + n_inner]);
        *(uint4*)(wt + ((((size_t)blk * KGRPS + kgrp) * GCPB + nn) << 3)) = *(const uint4*)tmp;
    }
}

// ---------------- grid barrier (monotone counter, agent scope) ----------------
__device__ __forceinline__ void grid_sync(unsigned* bar, unsigned target) {
    __syncthreads();
    if (threadIdx.x == 0) {
        __hip_atomic_fetch_add(bar, 1u, __ATOMIC_ACQ_REL, __HIP_MEMORY_SCOPE_AGENT);
        while (__hip_atomic_load(bar, __ATOMIC_ACQUIRE, __HIP_MEMORY_SCOPE_AGENT) < target) {
            __builtin_amdgcn_s_sleep(2);
        }
    }
    __syncthreads();
    __builtin_amdgcn_fence(__ATOMIC_ACQUIRE, "agent");
}

// ---------------- persistent LSTM kernel ----------------
__global__ __launch_bounds__(256, 1) void lstm_persist(
    const ushort_t* __restrict__ xbf,   // [T][B][DIN] bf16
    const ushort_t* __restrict__ wt,    // [NBLK][KGRPS][GCPB][8] bf16
    const float* __restrict__ h0, const float* __restrict__ C0,
    const float* __restrict__ b_i, const float* __restrict__ b_f,
    const float* __restrict__ b_o, const float* __restrict__ b_g,
    ushort_t* __restrict__ hbuf,        // [2][B][HID] bf16 double buffer
    unsigned* __restrict__ bar,
    float* __restrict__ out)            // hs [T][B][HID] then C [B][HID]
{
    __shared__ __align__(16) ushort_t Wl[KGRPS][GCPB][8];   // 96 KB
    __shared__ float gbuf[4][BATCH][GCPB + 1];              // 33 KB partials
    __shared__ float Cl[BATCH][HPB];
    __shared__ float biasl[GCPB];

    const int tid  = threadIdx.x;
    const int blk  = blockIdx.x;
    const int wave = tid >> 6;
    const int lane = tid & 63;
    const int j0   = blk * HPB;

    // stage W slice into LDS (96 KB = 6144 x uint4)
    {
        const uint4* src = (const uint4*)(wt + (size_t)blk * KGRPS * GCPB * 8);
        uint4* dst = (uint4*)(&Wl[0][0][0]);
        for (int i = tid; i < 6144; i += 256) dst[i] = src[i];
    }
    if (tid < GCPB) {
        int g = tid >> 3, j = tid & 7;
        const float* bp = (g == 0) ? b_i : (g == 1) ? b_f : (g == 2) ? b_o : b_g;
        biasl[tid] = bp[j0 + j];
    }
    for (int e = tid; e < BATCH * HPB; e += 256) {
        int b = e >> 3, j = e & 7;
        Cl[b][j] = C0[b * HID + j0 + j];
        hbuf[b * HID + j0 + j] = f2bf(h0[b * HID + j0 + j]);  // buffer 0
    }
    unsigned tgt = NBLK;
    grid_sync(bar, tgt); tgt += NBLK;   // init visible everywhere

    const int m_lane = lane & 15;
    const int koff   = (lane >> 4) * 8;
    int pb = 0;

    for (int t = 0; t < T_STEPS; ++t) {
        const ushort_t* hsrc = hbuf + pb * BATCH * HID;
        const ushort_t* xsrc = xbf + (size_t)t * BATCH * DIN;

        f32x4 acc[4][2];
#pragma unroll
        for (int rt = 0; rt < 4; ++rt)
#pragma unroll
            for (int ct = 0; ct < 2; ++ct)
                acc[rt][ct] = (f32x4){0.f, 0.f, 0.f, 0.f};

        // this wave's 12 k-chunks of 32
#pragma unroll
        for (int cc = 0; cc < 12; ++cc) {
            const int c = wave * 12 + cc;
            bf16x8 a[4];
            if (c < 32) {                       // h part
                const ushort_t* ap = hsrc + c * 32 + koff;
#pragma unroll
                for (int rt = 0; rt < 4; ++rt)
                    a[rt] = *(const bf16x8*)(ap + (size_t)(rt * 16 + m_lane) * HID);
            } else {                            // x part
                const ushort_t* ap = xsrc + (c - 32) * 32 + koff;
#pragma unroll
                for (int rt = 0; rt < 4; ++rt)
                    a[rt] = *(const bf16x8*)(ap + (size_t)(rt * 16 + m_lane) * DIN);
            }
            const int kgrp = c * 4 + (lane >> 4);
            bf16x8 b0 = *(const bf16x8*)(&Wl[kgrp][m_lane][0]);
            bf16x8 b1 = *(const bf16x8*)(&Wl[kgrp][16 + m_lane][0]);
#pragma unroll
            for (int rt = 0; rt < 4; ++rt) {
                acc[rt][0] = __builtin_amdgcn_mfma_f32_16x16x32_bf16(a[rt], b0, acc[rt][0], 0, 0, 0);
                acc[rt][1] = __builtin_amdgcn_mfma_f32_16x16x32_bf16(a[rt], b1, acc[rt][1], 0, 0, 0);
            }
        }

        // write K-partials: D[row=(lane>>4)*4+r][col=lane&15]
#pragma unroll
        for (int rt = 0; rt < 4; ++rt)
#pragma unroll
            for (int ct = 0; ct < 2; ++ct)
#pragma unroll
                for (int r = 0; r < 4; ++r)
                    gbuf[wave][rt * 16 + (lane >> 4) * 4 + r][ct * 16 + m_lane] = acc[rt][ct][r];
        __syncthreads();

        // pointwise LSTM update: 512 elements, 2 per thread
        for (int e = tid; e < BATCH * HPB; e += 256) {
            int b = e >> 3, j = e & 7;
            float pre[4];
#pragma unroll
            for (int g = 0; g < 4; ++g) {
                int col = g * 8 + j;
                pre[g] = biasl[col] + gbuf[0][b][col] + gbuf[1][b][col]
                                    + gbuf[2][b][col] + gbuf[3][b][col];
            }
            float ig = sigmoidf_(pre[0]);
            float fg = sigmoidf_(pre[1]);
            float og = sigmoidf_(pre[2]);
            float gg = tanhf(pre[3]);
            float c_new = fg * Cl[b][j] + ig * gg;
            Cl[b][j] = c_new;
            float h_new = og * tanhf(c_new);
            out[(size_t)t * BATCH * HID + b * HID + j0 + j] = h_new;
            hbuf[(1 - pb) * BATCH * HID + b * HID + j0 + j] = f2bf(h_new);
            if (t == T_STEPS - 1)
                out[(size_t)T_STEPS * BATCH * HID + b * HID + j0 + j] = c_new;
        }

        grid_sync(bar, tgt); tgt += NBLK;
        pb ^= 1;
    }
}

extern "C" void kernel_launch(void* const* d_in, const int* in_sizes, int n_in,
                              void* d_out, int out_size, void* d_ws, size_t ws_size,
                              hipStream_t stream) {
    (void)in_sizes; (void)n_in; (void)out_size; (void)ws_size;
    const float* x  = (const float*)d_in[0];
    const float* h0 = (const float*)d_in[1];
    const float* C0 = (const float*)d_in[2];
    const float* Wi = (const float*)d_in[3];
    const float* bi = (const float*)d_in[4];
    const float* Wf = (const float*)d_in[5];
    const float* bf = (const float*)d_in[6];
    const float* Wo = (const float*)d_in[7];
    const float* bo = (const float*)d_in[8];
    const float* Wg = (const float*)d_in[9];
    const float* bg = (const float*)d_in[10];
    float* out = (float*)d_out;

    char* ws = (char*)d_ws;
    unsigned*  bar  = (unsigned*)ws;                                  // 1 KB
    ushort_t*  hbuf = (ushort_t*)(ws + 1024);                         // 256 KB
    ushort_t*  xb   = (ushort_t*)(ws + 1024 + 262144);                // 32 MB
    ushort_t*  wt   = (ushort_t*)(ws + 1024 + 262144 + 33554432);     // 12 MB
    // total ws use ~46.4 MB

    hipMemsetAsync(bar, 0, 1024, stream);
    cvt_x<<<8192, 256, 0, stream>>>(x, xb, (T_STEPS * BATCH * DIN) / 8);
    xpose_w<<<dim3(24, 16, 4), 256, 0, stream>>>(Wi, Wf, Wo, Wg, wt);
    lstm_persist<<<NBLK, 256, 0, stream>>>(xb, wt, h0, C0, bi, bf, bo, bg, hbuf, bar, out);
}

// Round 2
// 7134.701 us; speedup vs baseline: 1.4417x; 1.4417x over previous
//
#include <hip/hip_runtime.h>
#include <hip/hip_bf16.h>
#include <stdint.h>

#define T_STEPS 512
#define BATCH   64
#define DIN     512
#define HID     1024
#define KDIM    1536        // HID + DIN (concat order: h then x)
#define NBLK    128         // persistent blocks (1 per CU, <=256 CUs)
#define HPB     8           // hidden cols per block
#define GCPB    32          // gate cols per block = 4 gates * HPB
#define NCHUNK  48          // KDIM / 32
#define KGRPS   192         // KDIM / 8

typedef __bf16 bf16x8 __attribute__((ext_vector_type(8)));
typedef float  f32x4  __attribute__((ext_vector_type(4)));
typedef unsigned short ushort_t;

__device__ __forceinline__ ushort_t f2bf(float f) {
    union { float f; unsigned u; } v; v.f = f;
    unsigned u = v.u;
    u += 0x7FFFu + ((u >> 16) & 1u);   // RNE
    return (ushort_t)(u >> 16);
}

__device__ __forceinline__ float sigmoidf_(float x) {
    return 1.0f / (1.0f + __expf(-x));
}

// ---------------- prep kernel 1: x fp32 -> bf16 ----------------
__global__ void cvt_x(const float* __restrict__ x, ushort_t* __restrict__ xb, int n8) {
    int i = blockIdx.x * blockDim.x + threadIdx.x;
    if (i >= n8) return;
    float4 v0 = ((const float4*)x)[2 * i];
    float4 v1 = ((const float4*)x)[2 * i + 1];
    uint4 o;
    o.x = (unsigned)f2bf(v0.x) | ((unsigned)f2bf(v0.y) << 16);
    o.y = (unsigned)f2bf(v0.z) | ((unsigned)f2bf(v0.w) << 16);
    o.z = (unsigned)f2bf(v1.x) | ((unsigned)f2bf(v1.y) << 16);
    o.w = (unsigned)f2bf(v1.z) | ((unsigned)f2bf(v1.w) << 16);
    ((uint4*)xb)[i] = o;
}

// ---------------- prep kernel 2: transpose W into per-block chunk-major bf16 ----------------
// Output layout: wt[blk][kgrp][n][8] bf16, blk=hiddencol/8, n = gate*8 + hiddencol%8, k = kgrp*8+j
__global__ void xpose_w(const float* __restrict__ Wi, const float* __restrict__ Wf,
                        const float* __restrict__ Wo, const float* __restrict__ Wg,
                        ushort_t* __restrict__ wt) {
    __shared__ float tile[64][65];
    int kt = blockIdx.x, nt = blockIdx.y, g = blockIdx.z;
    const float* W = (g == 0) ? Wi : (g == 1) ? Wf : (g == 2) ? Wo : Wg;
    int k0 = kt * 64, n0 = nt * 64;
    int c = threadIdx.x & 63, r0 = threadIdx.x >> 6;
#pragma unroll
    for (int i = 0; i < 16; ++i) {
        int r = r0 + i * 4;
        tile[r][c] = W[(size_t)(k0 + r) * HID + n0 + c];
    }
    __syncthreads();
#pragma unroll
    for (int p = 0; p < 2; ++p) {
        int q = threadIdx.x + p * 256;          // 512 chunks of 8
        int n_inner = q & 7;
        int kgl = (q >> 3) & 7;
        int bl = q >> 6;                        // 0..7
        int n = n0 + bl * 8 + n_inner;          // hidden col
        int blk = n >> 3;
        int nn = g * 8 + (n & 7);
        int kgrp = (k0 >> 3) + kgl;
        __align__(16) ushort_t tmp[8];
#pragma unroll
        for (int j = 0; j < 8; ++j) tmp[j] = f2bf(tile[kgl * 8 + j][bl * 8 + n_inner]);
        *(uint4*)(wt + ((((size_t)blk * KGRPS + kgrp) * GCPB + nn) << 3)) = *(const uint4*)tmp;
    }
}

// ---------------- persistent LSTM kernel ----------------
__global__ __launch_bounds__(256, 1) void lstm_persist(
    const ushort_t* __restrict__ xbf,   // [T][B][DIN] bf16
    const ushort_t* __restrict__ wt,    // [NBLK][KGRPS][GCPB][8] bf16
    const float* __restrict__ h0, const float* __restrict__ C0,
    const float* __restrict__ b_i, const float* __restrict__ b_f,
    const float* __restrict__ b_o, const float* __restrict__ b_g,
    ushort_t* __restrict__ hbuf,        // [2][B][HID] bf16 double buffer
    unsigned* __restrict__ flags,       // [NBLK] at 32-uint (128B) spacing
    float* __restrict__ out)            // hs [T][B][HID] then C [B][HID]
{
    __shared__ __align__(16) ushort_t Wl[KGRPS][GCPB][8];   // 96 KB
    __shared__ float gbuf[4][BATCH][GCPB + 1];              // 33 KB partials
    __shared__ float Cl[BATCH][HPB];
    __shared__ float biasl[GCPB];

    const int tid  = threadIdx.x;
    const int blk  = blockIdx.x;
    const int wave = tid >> 6;
    const int lane = tid & 63;
    const int j0   = blk * HPB;

    // stage W slice into LDS (96 KB = 6144 x uint4)
    {
        const uint4* src = (const uint4*)(wt + (size_t)blk * KGRPS * GCPB * 8);
        uint4* dst = (uint4*)(&Wl[0][0][0]);
        for (int i = tid; i < 6144; i += 256) dst[i] = src[i];
    }
    if (tid < GCPB) {
        int g = tid >> 3, j = tid & 7;
        const float* bp = (g == 0) ? b_i : (g == 1) ? b_f : (g == 2) ? b_o : b_g;
        biasl[tid] = bp[j0 + j];
    }
    for (int e = tid; e < BATCH * HPB; e += 256) {
        int b = e >> 3, j = e & 7;
        Cl[b][j] = C0[b * HID + j0 + j];
        hbuf[b * HID + j0 + j] = f2bf(h0[b * HID + j0 + j]);  // buffer 0
    }
    __syncthreads();
    if (tid == 0)
        __hip_atomic_store(&flags[blk * 32], 1u, __ATOMIC_RELEASE, __HIP_MEMORY_SCOPE_AGENT);

    const int m_lane = lane & 15;
    const int quad   = lane >> 4;
    const int koff   = quad * 8;
    int pb = 0;

    for (int t = 0; t < T_STEPS; ++t) {
        const ushort_t* hsrc = hbuf + pb * BATCH * HID;
        const ushort_t* xsrc = xbf + (size_t)t * BATCH * DIN;

        f32x4 acc[4][2];
#pragma unroll
        for (int rt = 0; rt < 4; ++rt)
#pragma unroll
            for (int ct = 0; ct < 2; ++ct)
                acc[rt][ct] = (f32x4){0.f, 0.f, 0.f, 0.f};

        // ---- x part first (independent of h -> overlaps barrier wait, stays before L2 inv)
#pragma unroll
        for (int cc = 0; cc < 4; ++cc) {
            const int c = 32 + wave * 4 + cc;   // x chunks 32..47
            const ushort_t* ap = xsrc + (c - 32) * 32 + koff;
            bf16x8 a[4];
#pragma unroll
            for (int rt = 0; rt < 4; ++rt)
                a[rt] = *(const bf16x8*)(ap + (size_t)(rt * 16 + m_lane) * DIN);
            const int kgrp = c * 4 + quad;
            bf16x8 b0 = *(const bf16x8*)(&Wl[kgrp][m_lane][0]);
            bf16x8 b1 = *(const bf16x8*)(&Wl[kgrp][16 + m_lane][0]);
#pragma unroll
            for (int rt = 0; rt < 4; ++rt) {
                acc[rt][0] = __builtin_amdgcn_mfma_f32_16x16x32_bf16(a[rt], b0, acc[rt][0], 0, 0, 0);
                acc[rt][1] = __builtin_amdgcn_mfma_f32_16x16x32_bf16(a[rt], b1, acc[rt][1], 0, 0, 0);
            }
        }

        // ---- wait for all blocks' h(t) (decentralized flags, one line each)
        if (tid < NBLK) {
            while (__hip_atomic_load(&flags[tid * 32], __ATOMIC_RELAXED,
                                     __HIP_MEMORY_SCOPE_AGENT) < (unsigned)(t + 1))
                __builtin_amdgcn_s_sleep(1);
        }
        __syncthreads();
        __builtin_amdgcn_fence(__ATOMIC_ACQUIRE, "agent");

        // ---- h part (8 chunks per wave)
#pragma unroll
        for (int cc = 0; cc < 8; ++cc) {
            const int c = wave * 8 + cc;        // h chunks 0..31
            const ushort_t* ap = hsrc + c * 32 + koff;
            bf16x8 a[4];
#pragma unroll
            for (int rt = 0; rt < 4; ++rt)
                a[rt] = *(const bf16x8*)(ap + (size_t)(rt * 16 + m_lane) * HID);
            const int kgrp = c * 4 + quad;
            bf16x8 b0 = *(const bf16x8*)(&Wl[kgrp][m_lane][0]);
            bf16x8 b1 = *(const bf16x8*)(&Wl[kgrp][16 + m_lane][0]);
#pragma unroll
            for (int rt = 0; rt < 4; ++rt) {
                acc[rt][0] = __builtin_amdgcn_mfma_f32_16x16x32_bf16(a[rt], b0, acc[rt][0], 0, 0, 0);
                acc[rt][1] = __builtin_amdgcn_mfma_f32_16x16x32_bf16(a[rt], b1, acc[rt][1], 0, 0, 0);
            }
        }

        // write K-partials: D[row=(lane>>4)*4+r][col=lane&15]
#pragma unroll
        for (int rt = 0; rt < 4; ++rt)
#pragma unroll
            for (int ct = 0; ct < 2; ++ct)
#pragma unroll
                for (int r = 0; r < 4; ++r)
                    gbuf[wave][rt * 16 + quad * 4 + r][ct * 16 + m_lane] = acc[rt][ct][r];
        __syncthreads();

        // pointwise LSTM update: 512 elements, 2 per thread
        for (int e = tid; e < BATCH * HPB; e += 256) {
            int b = e >> 3, j = e & 7;
            float pre[4];
#pragma unroll
            for (int g = 0; g < 4; ++g) {
                int col = g * 8 + j;
                pre[g] = biasl[col] + gbuf[0][b][col] + gbuf[1][b][col]
                                    + gbuf[2][b][col] + gbuf[3][b][col];
            }
            float ig = sigmoidf_(pre[0]);
            float fg = sigmoidf_(pre[1]);
            float og = sigmoidf_(pre[2]);
            float gg = tanhf(pre[3]);
            float c_new = fg * Cl[b][j] + ig * gg;
            Cl[b][j] = c_new;
            float h_new = og * tanhf(c_new);
            out[(size_t)t * BATCH * HID + b * HID + j0 + j] = h_new;
            hbuf[(1 - pb) * BATCH * HID + b * HID + j0 + j] = f2bf(h_new);
            if (t == T_STEPS - 1)
                out[(size_t)T_STEPS * BATCH * HID + b * HID + j0 + j] = c_new;
        }

        __syncthreads();   // all h stores issued+drained (each wave waits vmcnt before barrier)
        if (tid == 0)
            __hip_atomic_store(&flags[blk * 32], (unsigned)(t + 2), __ATOMIC_RELEASE,
                               __HIP_MEMORY_SCOPE_AGENT);
        pb ^= 1;
    }
}

extern "C" void kernel_launch(void* const* d_in, const int* in_sizes, int n_in,
                              void* d_out, int out_size, void* d_ws, size_t ws_size,
                              hipStream_t stream) {
    (void)in_sizes; (void)n_in; (void)out_size; (void)ws_size;
    const float* x  = (const float*)d_in[0];
    const float* h0 = (const float*)d_in[1];
    const float* C0 = (const float*)d_in[2];
    const float* Wi = (const float*)d_in[3];
    const float* bi = (const float*)d_in[4];
    const float* Wf = (const float*)d_in[5];
    const float* bf = (const float*)d_in[6];
    const float* Wo = (const float*)d_in[7];
    const float* bo = (const float*)d_in[8];
    const float* Wg = (const float*)d_in[9];
    const float* bg = (const float*)d_in[10];
    float* out = (float*)d_out;

    char* ws = (char*)d_ws;
    unsigned*  flags = (unsigned*)ws;                                  // 16 KB (128 x 128B)
    ushort_t*  hbuf  = (ushort_t*)(ws + 16384);                        // 256 KB
    ushort_t*  xb    = (ushort_t*)(ws + 16384 + 262144);               // 32 MB
    ushort_t*  wt    = (ushort_t*)(ws + 16384 + 262144 + 33554432);    // 12 MB

    hipMemsetAsync(flags, 0, 16384, stream);
    cvt_x<<<8192, 256, 0, stream>>>(x, xb, (T_STEPS * BATCH * DIN) / 8);
    xpose_w<<<dim3(24, 16, 4), 256, 0, stream>>>(Wi, Wf, Wo, Wg, wt);
    lstm_persist<<<NBLK, 256, 0, stream>>>(xb, wt, h0, C0, bi, bf, bo, bg, hbuf, flags, out);
}

// Round 3
// 6122.923 us; speedup vs baseline: 1.6799x; 1.1652x over previous
//
#include <hip/hip_runtime.h>
#include <hip/hip_bf16.h>
#include <stdint.h>

#define T_STEPS 512
#define BATCH   64
#define DIN     512
#define HID     1024
#define KDIM    1536        // HID + DIN (concat order: h then x)
#define NBLK    128         // persistent blocks (1 per CU, <=256 CUs)
#define HPB     8           // hidden cols per block
#define GCPB    32          // gate cols per block = 4 gates * HPB
#define KGRPS   192         // KDIM / 8

typedef __bf16 bf16x8 __attribute__((ext_vector_type(8)));
typedef float  f32x4  __attribute__((ext_vector_type(4)));
typedef unsigned short ushort_t;
typedef unsigned long long u64_t;

__device__ __forceinline__ ushort_t f2bf(float f) {
    union { float f; unsigned u; } v; v.f = f;
    unsigned u = v.u;
    u += 0x7FFFu + ((u >> 16) & 1u);   // RNE
    return (ushort_t)(u >> 16);
}

__device__ __forceinline__ float fast_sig(float x) {
    return __builtin_amdgcn_rcpf(1.0f + __expf(-x));
}
__device__ __forceinline__ float fast_tanh(float x) {
    // 1 - 2/(e^{2x}+1); exp overflow -> inf -> rcp -> 0 -> 1  (correct limit)
    float e = __expf(2.0f * x);
    return 1.0f - 2.0f * __builtin_amdgcn_rcpf(e + 1.0f);
}

// ---------------- prep kernel 1: x fp32 -> bf16 ----------------
__global__ void cvt_x(const float* __restrict__ x, ushort_t* __restrict__ xb, int n8) {
    int i = blockIdx.x * blockDim.x + threadIdx.x;
    if (i >= n8) return;
    float4 v0 = ((const float4*)x)[2 * i];
    float4 v1 = ((const float4*)x)[2 * i + 1];
    uint4 o;
    o.x = (unsigned)f2bf(v0.x) | ((unsigned)f2bf(v0.y) << 16);
    o.y = (unsigned)f2bf(v0.z) | ((unsigned)f2bf(v0.w) << 16);
    o.z = (unsigned)f2bf(v1.x) | ((unsigned)f2bf(v1.y) << 16);
    o.w = (unsigned)f2bf(v1.z) | ((unsigned)f2bf(v1.w) << 16);
    ((uint4*)xb)[i] = o;
}

// ---------------- prep kernel 2: transpose W into per-block chunk-major bf16 ----------------
// wt[blk][kgrp][n][8] bf16, blk=hiddencol/8, n = gate*8 + hiddencol%8, k = kgrp*8+j
__global__ void xpose_w(const float* __restrict__ Wi, const float* __restrict__ Wf,
                        const float* __restrict__ Wo, const float* __restrict__ Wg,
                        ushort_t* __restrict__ wt) {
    __shared__ float tile[64][65];
    int kt = blockIdx.x, nt = blockIdx.y, g = blockIdx.z;
    const float* W = (g == 0) ? Wi : (g == 1) ? Wf : (g == 2) ? Wo : Wg;
    int k0 = kt * 64, n0 = nt * 64;
    int c = threadIdx.x & 63, r0 = threadIdx.x >> 6;
#pragma unroll
    for (int i = 0; i < 16; ++i) {
        int r = r0 + i * 4;
        tile[r][c] = W[(size_t)(k0 + r) * HID + n0 + c];
    }
    __syncthreads();
#pragma unroll
    for (int p = 0; p < 2; ++p) {
        int q = threadIdx.x + p * 256;
        int n_inner = q & 7;
        int kgl = (q >> 3) & 7;
        int bl = q >> 6;
        int n = n0 + bl * 8 + n_inner;
        int blk = n >> 3;
        int nn = g * 8 + (n & 7);
        int kgrp = (k0 >> 3) + kgl;
        __align__(16) ushort_t tmp[8];
#pragma unroll
        for (int j = 0; j < 8; ++j) tmp[j] = f2bf(tile[kgl * 8 + j][bl * 8 + n_inner]);
        *(uint4*)(wt + ((((size_t)blk * KGRPS + kgrp) * GCPB + nn) << 3)) = *(const uint4*)tmp;
    }
}

// ---------------- persistent LSTM kernel ----------------
__global__ __launch_bounds__(256, 1) void lstm_persist(
    const ushort_t* __restrict__ xbf,   // [T][B][DIN] bf16
    const ushort_t* __restrict__ wt,    // [NBLK][KGRPS][GCPB][8] bf16
    const float* __restrict__ h0, const float* __restrict__ C0,
    const float* __restrict__ b_i, const float* __restrict__ b_f,
    const float* __restrict__ b_o, const float* __restrict__ b_g,
    ushort_t* __restrict__ hbuf,        // [2][B][HID] bf16 double buffer
    unsigned* __restrict__ flags,       // [NBLK] at 32-uint (128B) spacing
    float* __restrict__ out)            // hs [T][B][HID] then C [B][HID]
{
    __shared__ __align__(16) ushort_t Wl[KGRPS][GCPB][8];   // 96 KB
    __shared__ float gbuf[4][BATCH][GCPB + 1];              // ~33.8 KB partials
    __shared__ float Cl[BATCH][HPB + 1];
    __shared__ float biasl[GCPB];

    const int tid  = threadIdx.x;
    const int blk  = blockIdx.x;
    const int wave = tid >> 6;
    const int lane = tid & 63;
    const int j0   = blk * HPB;

    // stage W slice into LDS (96 KB = 6144 x uint4)
    {
        const uint4* src = (const uint4*)(wt + (size_t)blk * KGRPS * GCPB * 8);
        uint4* dst = (uint4*)(&Wl[0][0][0]);
        for (int i = tid; i < 6144; i += 256) dst[i] = src[i];
    }
    if (tid < GCPB) {
        int g = tid >> 3, j = tid & 7;
        const float* bp = (g == 0) ? b_i : (g == 1) ? b_f : (g == 2) ? b_o : b_g;
        biasl[tid] = bp[j0 + j];
    }
    if (tid < 128) {
        int b = tid >> 1, jh = (tid & 1) * 4;
#pragma unroll
        for (int jj = 0; jj < 4; ++jj)
            Cl[b][jh + jj] = C0[b * HID + j0 + jh + jj];
        u64_t pk = 0;
#pragma unroll
        for (int jj = 0; jj < 4; ++jj)
            pk |= (u64_t)f2bf(h0[b * HID + j0 + jh + jj]) << (16 * jj);
        __hip_atomic_store((u64_t*)(hbuf + b * HID + j0 + jh), pk,
                           __ATOMIC_RELAXED, __HIP_MEMORY_SCOPE_AGENT);
    }
    asm volatile("s_waitcnt vmcnt(0)" ::: "memory");
    __syncthreads();
    if (tid == 0)
        __hip_atomic_store(&flags[blk * 32], 1u, __ATOMIC_RELAXED, __HIP_MEMORY_SCOPE_AGENT);

    const int m_lane = lane & 15;
    const int quad   = lane >> 4;
    const int koff   = quad * 8;
    int pb = 0;

    for (int t = 0; t < T_STEPS; ++t) {
        const ushort_t* hsrc = hbuf + pb * BATCH * HID;
        const ushort_t* xsrc = xbf + (size_t)t * BATCH * DIN;

        f32x4 acc[4][2];
#pragma unroll
        for (int rt = 0; rt < 4; ++rt)
#pragma unroll
            for (int ct = 0; ct < 2; ++ct)
                acc[rt][ct] = (f32x4){0.f, 0.f, 0.f, 0.f};

        // ---- x part first (independent of h -> overlaps flag wait)
#pragma unroll
        for (int cc = 0; cc < 4; ++cc) {
            const int c = 32 + wave * 4 + cc;   // x chunks 32..47
            const ushort_t* ap = xsrc + (c - 32) * 32 + koff;
            bf16x8 a[4];
#pragma unroll
            for (int rt = 0; rt < 4; ++rt)
                a[rt] = *(const bf16x8*)(ap + (size_t)(rt * 16 + m_lane) * DIN);
            const int kgrp = c * 4 + quad;
            bf16x8 b0 = *(const bf16x8*)(&Wl[kgrp][m_lane][0]);
            bf16x8 b1 = *(const bf16x8*)(&Wl[kgrp][16 + m_lane][0]);
#pragma unroll
            for (int rt = 0; rt < 4; ++rt) {
                acc[rt][0] = __builtin_amdgcn_mfma_f32_16x16x32_bf16(a[rt], b0, acc[rt][0], 0, 0, 0);
                acc[rt][1] = __builtin_amdgcn_mfma_f32_16x16x32_bf16(a[rt], b1, acc[rt][1], 0, 0, 0);
            }
        }

        // ---- wait for all blocks' h(t)
        if (tid < NBLK) {
            while (__hip_atomic_load(&flags[tid * 32], __ATOMIC_RELAXED,
                                     __HIP_MEMORY_SCOPE_AGENT) < (unsigned)(t + 1))
                __builtin_amdgcn_s_sleep(1);
        }
        __syncthreads();
        __builtin_amdgcn_fence(__ATOMIC_ACQUIRE, "agent");   // buffer_inv only (no wbl2)

        // ---- h part (8 chunks per wave), normal loads (L2-shared per XCD)
#pragma unroll
        for (int cc = 0; cc < 8; ++cc) {
            const int c = wave * 8 + cc;        // h chunks 0..31
            const ushort_t* ap = hsrc + c * 32 + koff;
            bf16x8 a[4];
#pragma unroll
            for (int rt = 0; rt < 4; ++rt)
                a[rt] = *(const bf16x8*)(ap + (size_t)(rt * 16 + m_lane) * HID);
            const int kgrp = c * 4 + quad;
            bf16x8 b0 = *(const bf16x8*)(&Wl[kgrp][m_lane][0]);
            bf16x8 b1 = *(const bf16x8*)(&Wl[kgrp][16 + m_lane][0]);
#pragma unroll
            for (int rt = 0; rt < 4; ++rt) {
                acc[rt][0] = __builtin_amdgcn_mfma_f32_16x16x32_bf16(a[rt], b0, acc[rt][0], 0, 0, 0);
                acc[rt][1] = __builtin_amdgcn_mfma_f32_16x16x32_bf16(a[rt], b1, acc[rt][1], 0, 0, 0);
            }
        }

        // write K-partials: D[row=(lane>>4)*4+r][col=lane&15]
#pragma unroll
        for (int rt = 0; rt < 4; ++rt)
#pragma unroll
            for (int ct = 0; ct < 2; ++ct)
#pragma unroll
                for (int r = 0; r < 4; ++r)
                    gbuf[wave][rt * 16 + quad * 4 + r][ct * 16 + m_lane] = acc[rt][ct][r];
        __syncthreads();

        // pointwise: 128 threads, each owns (batch row b, 4 cols)
        float hv[4], cv[4];
        int b = tid >> 1, jh = (tid & 1) * 4;
        if (tid < 128) {
#pragma unroll
            for (int jj = 0; jj < 4; ++jj) {
                int j = jh + jj;
                float pre[4];
#pragma unroll
                for (int g = 0; g < 4; ++g) {
                    int col = g * 8 + j;
                    pre[g] = biasl[col] + gbuf[0][b][col] + gbuf[1][b][col]
                                        + gbuf[2][b][col] + gbuf[3][b][col];
                }
                float ig = fast_sig(pre[0]);
                float fg = fast_sig(pre[1]);
                float og = fast_sig(pre[2]);
                float gg = fast_tanh(pre[3]);
                float c_new = fg * Cl[b][jh + jj] + ig * gg;
                Cl[b][jh + jj] = c_new;
                cv[jj] = c_new;
                hv[jj] = og * fast_tanh(c_new);
            }
            u64_t pk = (u64_t)f2bf(hv[0]) | ((u64_t)f2bf(hv[1]) << 16)
                     | ((u64_t)f2bf(hv[2]) << 32) | ((u64_t)f2bf(hv[3]) << 48);
            __hip_atomic_store((u64_t*)(hbuf + (1 - pb) * BATCH * HID + b * HID + j0 + jh),
                               pk, __ATOMIC_RELAXED, __HIP_MEMORY_SCOPE_AGENT);
        }
        asm volatile("s_waitcnt vmcnt(0)" ::: "memory");   // h stores at coherence point
        __syncthreads();
        if (tid == 0)
            __hip_atomic_store(&flags[blk * 32], (unsigned)(t + 2), __ATOMIC_RELAXED,
                               __HIP_MEMORY_SCOPE_AGENT);

        // off critical path: fp32 hs (+ final C) output
        if (tid < 128) {
            float4 o4; o4.x = hv[0]; o4.y = hv[1]; o4.z = hv[2]; o4.w = hv[3];
            *(float4*)(out + (size_t)t * BATCH * HID + b * HID + j0 + jh) = o4;
            if (t == T_STEPS - 1) {
                float4 c4; c4.x = cv[0]; c4.y = cv[1]; c4.z = cv[2]; c4.w = cv[3];
                *(float4*)(out + (size_t)T_STEPS * BATCH * HID + b * HID + j0 + jh) = c4;
            }
        }
        pb ^= 1;
    }
}

extern "C" void kernel_launch(void* const* d_in, const int* in_sizes, int n_in,
                              void* d_out, int out_size, void* d_ws, size_t ws_size,
                              hipStream_t stream) {
    (void)in_sizes; (void)n_in; (void)out_size; (void)ws_size;
    const float* x  = (const float*)d_in[0];
    const float* h0 = (const float*)d_in[1];
    const float* C0 = (const float*)d_in[2];
    const float* Wi = (const float*)d_in[3];
    const float* bi = (const float*)d_in[4];
    const float* Wf = (const float*)d_in[5];
    const float* bf = (const float*)d_in[6];
    const float* Wo = (const float*)d_in[7];
    const float* bo = (const float*)d_in[8];
    const float* Wg = (const float*)d_in[9];
    const float* bg = (const float*)d_in[10];
    float* out = (float*)d_out;

    char* ws = (char*)d_ws;
    unsigned*  flags = (unsigned*)ws;                                  // 16 KB (128 x 128B)
    ushort_t*  hbuf  = (ushort_t*)(ws + 16384);                        // 256 KB
    ushort_t*  xb    = (ushort_t*)(ws + 16384 + 262144);               // 32 MB
    ushort_t*  wt    = (ushort_t*)(ws + 16384 + 262144 + 33554432);    // 12 MB

    hipMemsetAsync(flags, 0, 16384, stream);
    cvt_x<<<8192, 256, 0, stream>>>(x, xb, (T_STEPS * BATCH * DIN) / 8);
    xpose_w<<<dim3(24, 16, 4), 256, 0, stream>>>(Wi, Wf, Wo, Wg, wt);
    lstm_persist<<<NBLK, 256, 0, stream>>>(xb, wt, h0, C0, bi, bf, bo, bg, hbuf, flags, out);
}